// Round 14
// baseline (376.241 us; speedup 1.0000x reference)
//
#include <hip/hip_runtime.h>
#include <math.h>

// Problem constants (from reference)
#define N_NODES 100000
#define N_EDGES 1600000
#define E2      (N_NODES + N_EDGES)   // edges incl. self-loops = 1,700,000
#define IN_C    128
#define HID     64
#define HEADS   4
#define HH      256                    // HEADS*HID
#define OUT_C   2
#define NEG_SLOPE 0.2f

#define SB   1024                      // elements per scan block
#define NSB  ((N_NODES + SB - 1) / SB) // 98
#define NRANGE 4                       // dst ranges (bands of 25000 nodes)
#define RDIV   25000
#define BINS   RDIV                    // histogram bins per band (u16)
#define BINW   (BINS / 2)              // packed u32 words in LDS = 12500 (50KB)
#define NBK    100                     // chunks per band (hist blocks)
#define CHUNK  (N_EDGES / NBK)         // 16000 edges per chunk
#define C4     (CHUNK / 4)             // 4000 int4 per chunk
#define HTH    1024                    // hist block size (occupancy lever)
#define CITER4 ((C4 + HTH - 1) / HTH)  // 4
#define NHB    (NRANGE * NBK)          // 400 hist blocks
#define NFC    (N_EDGES / 256)         // 6250 fill blocks (unbanded)
#define RT     10                      // row-tiles (16 rows) per gemm3m block
#define NT1    6250                    // gemm1 row-tiles (16 rows each)
#define NGEMM1 ((NT1 + 3) / 4)         // 1563 gemm1 blocks (4 tiles each)

typedef __attribute__((ext_vector_type(8))) short bf16x8;
typedef __attribute__((ext_vector_type(4))) float f32x4;

__device__ __forceinline__ float bf2f(unsigned short u) {
    return __uint_as_float(((unsigned)u) << 16);
}
__device__ __forceinline__ unsigned short f2bf(float f) {
    unsigned u = __float_as_uint(f);
    u += 0x7fffu + ((u >> 16) & 1u);   // RNE
    return (unsigned short)(u >> 16);
}

// ---------------- history ----------------
// r1: global-atomic hist 74us wall. r3: LDS-cursor fill 90us. r5: banded
// fill 8x re-read. r6: fill+gemm1 L2 thrash. r7/r8 regressions reverted r9.
// r12 = 363us best (agg1a unroll4+dinv-fold, hist@1024th, merged agg2u).
// r13 (+11us): agg2u split+unroll8 and scan1 atomicAdd rework — BOTH
// REVERTED here to exact r12 forms.
// r14 (this round), ONE change: agg1a's gather loads were CONDITIONAL
// (if idx<cnt), so the compiler kept VGPR=16 and ~1 gather in flight
// (59.5us at 22% HBM / 50% VALU vs ~15us L3 floor). Loads are now
// UNCONDITIONAL with clamped index (row 0 always valid); only the
// accumulate stays predicated -> 4 independent gathers in flight.
// WS: hp16 (20 MB) + rank16 (3.2 MB) ALIAS the front of ub — both die
// after k_fill; ub is first written by k_agg2u (later in stream order).

// prep: b<64: W2t transpose; b in [64,66): wsdt; b in [66,98): W1t.
__global__ __launch_bounds__(256) void k_prep(const float* __restrict__ W2,
        const float* __restrict__ W1,
        const float* __restrict__ att_src, const float* __restrict__ att_dst,
        unsigned short* __restrict__ W2t, unsigned short* __restrict__ wsdt,
        unsigned short* __restrict__ W1t) {
    int b = blockIdx.x, t = threadIdx.x;
    if (b < 64) {                       // W2t[n*64+k] = bf16(W2[k][n])
        int g = b * 256 + t;            // g = k*256 + n
        int k = g >> 8, n = g & 255;
        W2t[n * 64 + k] = f2bf(W2[g]);
        return;
    }
    if (b < 66) {                       // wsdt[o*64+k], cols 8..15 zeroed
        int g = (b - 64) * 256 + t;     // 0..511
        wsdt[512 + g] = 0;
        int k = g >> 3, o = g & 7;
        int h = o & 3;
        const float* att = (o < 4) ? att_src : att_dst;
        float acc = 0.f;
        const float* wrow = W2 + (size_t)k * HH + h * 64;
        const float* arow = att + h * 64;
        for (int c = 0; c < 64; ++c) acc = fmaf(wrow[c], arow[c], acc);
        wsdt[o * 64 + k] = f2bf(acc);
        return;
    }
    // W1t[n*128+k] = bf16(W1[k][n])
    int g = (b - 66) * 256 + t;         // 0..8191, g = k*64 + n
    int k = g >> 6, n = g & 63;
    W1t[n * 128 + k] = f2bf(W1[g]);
}

// Banded-LDS hist, int4 loads, PACKED u16 bins (2 per u32; counts < 16000
// so neither half can carry). b = k*4 + r: the 4 band-copies of a chunk are
// dispatch-adjacent (round-robin XCDs) so dst bytes are L3-served after the
// first miss. 1024 threads/block: 2 blocks/CU = 32 waves/CU (HW max).
__global__ __launch_bounds__(HTH) void k_hist(const int* __restrict__ ei,
        unsigned short* __restrict__ hp16, unsigned short* __restrict__ rank16) {
    __shared__ unsigned int hh[BINW];   // 50 KB, 2 bins/word
    int b = blockIdx.x, t = threadIdx.x;
    int r = b & 3, k = b >> 2;          // band, chunk
    for (int i = t; i < BINW; i += HTH) hh[i] = 0u;
    __syncthreads();
    const int4* dp4 = (const int4*)(ei + N_EDGES + (size_t)k * CHUNK);
    unsigned short* rp = rank16 + (size_t)k * CHUNK;
    int lo = r * RDIV;
#pragma unroll 2
    for (int it = 0; it < CITER4; ++it) {
        int i4 = it * HTH + t;
        if (i4 < C4) {
            int4 v = dp4[i4];
            int base = i4 * 4;
            int d0 = v.x - lo, d1 = v.y - lo, d2 = v.z - lo, d3 = v.w - lo;
            if ((unsigned)d0 < (unsigned)RDIV) {
                unsigned sh = (d0 & 1) * 16;
                unsigned old = atomicAdd(&hh[d0 >> 1], 1u << sh);
                rp[base + 0] = (unsigned short)(old >> sh);
            }
            if ((unsigned)d1 < (unsigned)RDIV) {
                unsigned sh = (d1 & 1) * 16;
                unsigned old = atomicAdd(&hh[d1 >> 1], 1u << sh);
                rp[base + 1] = (unsigned short)(old >> sh);
            }
            if ((unsigned)d2 < (unsigned)RDIV) {
                unsigned sh = (d2 & 1) * 16;
                unsigned old = atomicAdd(&hh[d2 >> 1], 1u << sh);
                rp[base + 2] = (unsigned short)(old >> sh);
            }
            if ((unsigned)d3 < (unsigned)RDIV) {
                unsigned sh = (d3 & 1) * 16;
                unsigned old = atomicAdd(&hh[d3 >> 1], 1u << sh);
                rp[base + 3] = (unsigned short)(old >> sh);
            }
        }
    }
    __syncthreads();
    // table writeout: packed u32 layout == consecutive u16 bins (LE)
    unsigned* hp = (unsigned*)(hp16 + (size_t)(r * NBK + k) * BINS);
    for (int i = t; i < BINW; i += HTH) hp[i] = hh[i];
}

// scan1 (r12 form): cnt[i] = sum_k h[r][k][bin]; converts hp16 IN PLACE to
// exclusive prefixes over k; emits per-block degree sums -> bsum.
__global__ __launch_bounds__(256) void k_scan1(unsigned short* __restrict__ hp16,
        int* __restrict__ cnt, int* __restrict__ bsum) {
    int b = blockIdx.x, t = threadIdx.x;
    int s = 0;
#pragma unroll
    for (int u = 0; u < 4; ++u) {
        int i = b * SB + u * 256 + t;
        if (i < N_NODES) {
            int r = i / RDIV, bin = i - r * RDIV;
            unsigned short* p = hp16 + (size_t)r * NBK * BINS + bin;
            unsigned acc = 0;
            for (int k = 0; k < NBK; ++k) {
                unsigned short hv = p[(size_t)k * BINS];
                p[(size_t)k * BINS] = (unsigned short)acc;
                acc += hv;
            }
            cnt[i] = (int)acc;
            s += (int)acc + 1;           // +1 self-loop
        }
    }
#pragma unroll
    for (int off = 1; off < 64; off <<= 1) s += __shfl_xor(s, off);
    __shared__ int wsum[4];
    int lane = t & 63, wv = t >> 6;
    if (lane == 0) wsum[wv] = s;
    __syncthreads();
    if (t == 0) bsum[b] = (wsum[0] + wsum[1]) + (wsum[2] + wsum[3]);
}

// scan3: block b computes prefix over bsum[0..b) itself, scans its chunk
// (deg = cnt+1), writes rowptr + dinv, pre-places self-loops at slot 0.
__global__ __launch_bounds__(256) void k_scan3(const int* __restrict__ cnt,
        const int* __restrict__ bsum, int* __restrict__ rowptr,
        float* __restrict__ dinv, int* __restrict__ col) {
    int b = blockIdx.x, t = threadIdx.x;
    int lane = t & 63, wv = t >> 6;
    __shared__ int wred[4];
    {
        int v = (t < b) ? bsum[t] : 0;   // b <= 98 <= 256
#pragma unroll
        for (int off = 1; off < 64; off <<= 1) v += __shfl_xor(v, off);
        if (lane == 0) wred[wv] = v;
    }
    __syncthreads();
    int pre = (wred[0] + wred[1]) + (wred[2] + wred[3]);
    __syncthreads();

    int i = b * SB + t * 4;
    int c0 = 0, c1 = 0, c2 = 0, c3 = 0;
    if (i + 3 < N_NODES) {
        int4 v = *(const int4*)(cnt + i);
        c0 = v.x; c1 = v.y; c2 = v.z; c3 = v.w;
    } else if (i < N_NODES) {
        c0 = cnt[i];
        if (i + 1 < N_NODES) c1 = cnt[i + 1];
        if (i + 2 < N_NODES) c2 = cnt[i + 2];
    }
    int n0 = (i < N_NODES), n1 = (i + 1 < N_NODES),
        n2 = (i + 2 < N_NODES), n3 = (i + 3 < N_NODES);
    int d0 = c0 + n0, d1 = c1 + n1, d2 = c2 + n2, d3 = c3 + n3;  // degrees
    int s = (d0 + d1) + (d2 + d3);
    int inc = s;
#pragma unroll
    for (int off = 1; off < 64; off <<= 1) {
        int u = __shfl_up(inc, off);
        if (lane >= off) inc += u;
    }
    __shared__ int wtot[4];
    if (lane == 63) wtot[wv] = inc;
    __syncthreads();
    int base = pre + (inc - s);
    for (int w = 0; w < wv; ++w) base += wtot[w];
    if (n0) { rowptr[i]     = base;                dinv[i]     = rsqrtf((float)d0); col[base] = i; }
    if (n1) { rowptr[i + 1] = base + d0;           dinv[i + 1] = rsqrtf((float)d1); col[base + d0] = i + 1; }
    if (n2) { rowptr[i + 2] = base + d0 + d1;      dinv[i + 2] = rsqrtf((float)d2); col[base + d0 + d1] = i + 2; }
    if (n3) { rowptr[i + 3] = base + d0 + d1 + d2; dinv[i + 3] = rsqrtf((float)d3); col[base + d0 + d1 + d2] = i + 3; }
    if (b == 0 && t == 0) rowptr[N_NODES] = E2;
}

// gemm1d: xw1b = bf16(dinv[row] * (x @ W1)) — dinv FOLDED (r0 numerics).
__global__ __launch_bounds__(256) void k_gemm1d(const float* __restrict__ x,
        const unsigned short* __restrict__ W1t, const float* __restrict__ dinv,
        unsigned short* __restrict__ xw1b) {
    int t = threadIdx.x;
    int lane = t & 63, wv = t >> 6;
    int m = lane & 15, quad = lane >> 4;
    bf16x8 B[4][4];
#pragma unroll
    for (int ct = 0; ct < 4; ++ct)
#pragma unroll
        for (int ks = 0; ks < 4; ++ks)
            B[ct][ks] = *(const bf16x8*)(W1t + (size_t)(ct * 16 + m) * IN_C
                                         + ks * 32 + quad * 8);
    int tile = blockIdx.x * 4 + wv;
    if (tile >= NT1) return;
    int rbase = tile * 16;
    const float* xp = x + (size_t)(rbase + m) * IN_C + quad * 8;
    f32x4 c0 = {0.f, 0.f, 0.f, 0.f}, c1 = c0, c2 = c0, c3 = c0;
#pragma unroll
    for (int ks = 0; ks < 4; ++ks) {
        float4 f0 = *(const float4*)(xp + ks * 32);
        float4 f1 = *(const float4*)(xp + ks * 32 + 4);
        bf16x8 a;
        a[0] = (short)f2bf(f0.x); a[1] = (short)f2bf(f0.y);
        a[2] = (short)f2bf(f0.z); a[3] = (short)f2bf(f0.w);
        a[4] = (short)f2bf(f1.x); a[5] = (short)f2bf(f1.y);
        a[6] = (short)f2bf(f1.z); a[7] = (short)f2bf(f1.w);
        c0 = __builtin_amdgcn_mfma_f32_16x16x32_bf16(a, B[0][ks], c0, 0, 0, 0);
        c1 = __builtin_amdgcn_mfma_f32_16x16x32_bf16(a, B[1][ks], c1, 0, 0, 0);
        c2 = __builtin_amdgcn_mfma_f32_16x16x32_bf16(a, B[2][ks], c2, 0, 0, 0);
        c3 = __builtin_amdgcn_mfma_f32_16x16x32_bf16(a, B[3][ks], c3, 0, 0, 0);
    }
    int row0 = rbase + quad * 4;
    float4 dv = *(const float4*)(dinv + row0);   // 16B-aligned (row0 % 4 == 0)
    float dr[4] = {dv.x, dv.y, dv.z, dv.w};
#pragma unroll
    for (int ct = 0; ct < 4; ++ct) {
        f32x4 c = (ct == 0) ? c0 : (ct == 1) ? c1 : (ct == 2) ? c2 : c3;
        unsigned short* p = xw1b + (size_t)row0 * HID + ct * 16 + m;
#pragma unroll
        for (int r = 0; r < 4; ++r) p[(size_t)r * HID] = f2bf(c[r] * dr[r]);
    }
}

// fill: unbanded single-pass scatter, UNFUSED.
// pos = rowptr[d] + 1 + prefix[band][chunk][bin] + rank16[i].
__global__ void k_fill(const int* __restrict__ ei, const int* __restrict__ rowptr,
        const unsigned short* __restrict__ hp16,
        const unsigned short* __restrict__ rank16, int* __restrict__ col) {
    int i = blockIdx.x * 256 + threadIdx.x;  // NFC*256 == N_EDGES exactly
    int d = ei[N_EDGES + i];
    int s = ei[i];
    int r = d / RDIV;
    int bin = d - r * RDIV;
    int k = i / CHUNK;
    unsigned pos = (unsigned)rowptr[d] + 1u
                 + (unsigned)hp16[(size_t)(r * NBK + k) * BINS + bin]
                 + (unsigned)rank16[i];
    col[pos] = s;                           // slot 0 = self-loop
}

// ------- GCN1 aggregate + FUSED attention logits -------
// xw1b already carries dinv[src]. r14: gather loads made UNCONDITIONAL with
// clamped index (row 0 always valid) so the 4 unrolled {shfl,load} groups
// are independent and stay in flight; only the accumulate is predicated.
// (r13 PMC: VGPR stuck at 16 with conditional loads = 1 gather in flight.)
__global__ __launch_bounds__(256) void k_agg1a(const int* __restrict__ rowptr,
        const int* __restrict__ col, const unsigned short* __restrict__ xw1b,
        const float* __restrict__ dinv, const float* __restrict__ b1,
        const unsigned short* __restrict__ wsdt,
        unsigned short* __restrict__ h1b,
        float* __restrict__ a_s, float* __restrict__ a_d) {
    int t = threadIdx.x;
    int lane = t & 63;
    int d = blockIdx.x * 4 + (t >> 6);
    if (d >= N_NODES) return;
    int start = rowptr[d], end = rowptr[d + 1];
    int sub = lane >> 4;       // which of 4 edges in a group
    int cpos = lane & 15;      // channel quad (4 bf16)
    float4 acc = make_float4(0.f, 0.f, 0.f, 0.f);
    for (int base = start; base < end; base += 64) {
        int cnt = min(64, end - base);
        int sl = (base + lane < end) ? col[base + lane] : 0;
#pragma unroll 4
        for (int j = 0; j < cnt; j += 4) {
            int idx = j + sub;
            int sj = __shfl(sl, idx);
            int sjc = (idx < cnt) ? sj : 0;           // clamp: row 0 valid
            ushort4 v = ((const ushort4*)(xw1b + (unsigned)sjc * HID))[cpos];
            if (idx < cnt) {                           // predicated accumulate
                acc.x += bf2f(v.x);
                acc.y += bf2f(v.y);
                acc.z += bf2f(v.z);
                acc.w += bf2f(v.w);
            }
        }
    }
    acc.x += __shfl_xor(acc.x, 16); acc.y += __shfl_xor(acc.y, 16);
    acc.z += __shfl_xor(acc.z, 16); acc.w += __shfl_xor(acc.w, 16);
    acc.x += __shfl_xor(acc.x, 32); acc.y += __shfl_xor(acc.y, 32);
    acc.z += __shfl_xor(acc.z, 32); acc.w += __shfl_xor(acc.w, 32);
    // every lane now holds the fully-reduced quad for channels cpos*4..+3
    float di = dinv[d];
    float4 b = ((const float4*)b1)[cpos];
    float h0 = fmaf(acc.x, di, b.x); h0 = h0 > 0.f ? h0 : 0.f;
    float h1 = fmaf(acc.y, di, b.y); h1 = h1 > 0.f ? h1 : 0.f;
    float h2 = fmaf(acc.z, di, b.z); h2 = h2 > 0.f ? h2 : 0.f;
    float h3 = fmaf(acc.w, di, b.w); h3 = h3 > 0.f ? h3 : 0.f;
    ushort4 o = make_ushort4(f2bf(h0), f2bf(h1), f2bf(h2), f2bf(h3));
    if (lane < 16)
        ((ushort4*)(h1b + (size_t)d * HID))[cpos] = o;
    // attention dots on bf16-rounded values (== old k_attn's inputs)
    float r0 = bf2f(o.x), r1 = bf2f(o.y), r2 = bf2f(o.z), r3 = bf2f(o.w);
    int hsel = lane >> 4;                        // head 0..3
    ushort4 ws = ((const ushort4*)(wsdt + hsel * 64))[cpos];
    ushort4 wd = ((const ushort4*)(wsdt + (hsel + 4) * 64))[cpos];
    float ps = r0 * bf2f(ws.x) + r1 * bf2f(ws.y)
             + r2 * bf2f(ws.z) + r3 * bf2f(ws.w);
    float pd = r0 * bf2f(wd.x) + r1 * bf2f(wd.y)
             + r2 * bf2f(wd.z) + r3 * bf2f(wd.w);
#pragma unroll
    for (int mk = 1; mk < 16; mk <<= 1) {
        ps += __shfl_xor(ps, mk);
        pd += __shfl_xor(pd, mk);
    }
    if (cpos == 0) {
        a_s[d * 4 + hsel] = ps;
        a_d[d * 4 + hsel] = pd;
    }
}

// ---------------- GAT aggregate on h1 (agg commutes with W2) ----------------
// r12 form: merged single dispatch, 1 edge/iter, unroll 4.
__global__ __launch_bounds__(256) void k_agg2u(const int* __restrict__ rowptr,
        const int* __restrict__ col, const unsigned short* __restrict__ h1b,
        const float* __restrict__ a_s, const float* __restrict__ a_d,
        unsigned short* __restrict__ ub) {
    __shared__ int   ss[4][64];      // 1 KB
    __shared__ float sp[4][64][4];   // 4 KB
    int t = threadIdx.x;
    int lane = t & 63, wv = t >> 6;
    int d = blockIdx.x * 4 + wv;
    if (d >= N_NODES) return;
    const float4* as4 = (const float4*)a_s;
    float4 adv = ((const float4*)a_d)[d];
    int start = rowptr[d], end = rowptr[d + 1];

    float den0 = 0.f, den1 = 0.f, den2 = 0.f, den3 = 0.f;
    float acc0 = 0.f, acc1 = 0.f, acc2 = 0.f, acc3 = 0.f;
    for (int base = start; base < end; base += 64) {
        int cnt = min(64, end - base);
        float p0 = 0.f, p1 = 0.f, p2 = 0.f, p3 = 0.f;
        int s = 0;
        if (lane < cnt) {
            s = col[base + lane];
            float4 av = as4[s];
            float v;
            v = av.x + adv.x; v = v > 0.f ? v : NEG_SLOPE * v; p0 = __expf(v);
            v = av.y + adv.y; v = v > 0.f ? v : NEG_SLOPE * v; p1 = __expf(v);
            v = av.z + adv.z; v = v > 0.f ? v : NEG_SLOPE * v; p2 = __expf(v);
            v = av.w + adv.w; v = v > 0.f ? v : NEG_SLOPE * v; p3 = __expf(v);
            den0 += p0; den1 += p1; den2 += p2; den3 += p3;
        }
        ss[wv][lane] = s;                                  // wave-private LDS
        ((float4*)sp[wv])[lane] = make_float4(p0, p1, p2, p3);
#pragma unroll 4
        for (int j = 0; j < cnt; ++j) {
            int sj = ss[wv][j];                            // broadcast read
            float4 pj = ((const float4*)sp[wv])[j];        // broadcast read
            float v = bf2f(h1b[(unsigned)sj * 64u + (unsigned)lane]); // 2B/lane
            acc0 = fmaf(pj.x, v, acc0);
            acc1 = fmaf(pj.y, v, acc1);
            acc2 = fmaf(pj.z, v, acc2);
            acc3 = fmaf(pj.w, v, acc3);
        }
    }
#pragma unroll
    for (int mk = 1; mk < 64; mk <<= 1) {
        den0 += __shfl_xor(den0, mk);
        den1 += __shfl_xor(den1, mk);
        den2 += __shfl_xor(den2, mk);
        den3 += __shfl_xor(den3, mk);
    }
    float u0 = acc0 / (den0 + 1e-16f);
    float u1 = acc1 / (den1 + 1e-16f);
    float u2 = acc2 / (den2 + 1e-16f);
    float u3 = acc3 / (den3 + 1e-16f);
    unsigned short* up = ub + (size_t)d * HH;
    up[lane]       = f2bf(u0);
    up[64 + lane]  = f2bf(u1);
    up[128 + lane] = f2bf(u2);
    up[192 + lane] = f2bf(u3);
}

// ---------------- W2-apply + b2 + ELU + W3 + dinv, via MFMA -----------------
__global__ __launch_bounds__(256) void k_gemm3m(const unsigned short* __restrict__ ub,
        const unsigned short* __restrict__ W2t, const float* __restrict__ b2,
        const float* __restrict__ W3, const float* __restrict__ dinv,
        float2* __restrict__ xw3) {
    int t = threadIdx.x;
    int lane = t & 63, wv = t >> 6;
    int m = lane & 15, quad = lane >> 4;
    int nb = wv * 64 + m;            // lane's base output column (head = wv)
    bf16x8 B[4][2];
#pragma unroll
    for (int ct = 0; ct < 4; ++ct)
#pragma unroll
        for (int ks = 0; ks < 2; ++ks)
            B[ct][ks] = *(const bf16x8*)(W2t + (size_t)(nb + ct * 16) * 64
                                         + ks * 32 + quad * 8);
    float bv[4]; float2 w3v[4];
#pragma unroll
    for (int ct = 0; ct < 4; ++ct) {
        int n = nb + ct * 16;
        bv[ct] = b2[n];
        w3v[ct] = ((const float2*)W3)[n];
    }
    __shared__ float red[4][16][2];  // [wave][row][xy]
    int r0 = blockIdx.x * (RT * 16);
    for (int tile = 0; tile < RT; ++tile) {
        int rbase = r0 + tile * 16;
        const unsigned short* ap = ub + (size_t)(rbase + m) * HH + wv * 64 + quad * 8;
        bf16x8 a0 = *(const bf16x8*)(ap);
        bf16x8 a1 = *(const bf16x8*)(ap + 32);
        f32x4 c0 = {0.f, 0.f, 0.f, 0.f}, c1 = c0, c2 = c0, c3 = c0;
        c0 = __builtin_amdgcn_mfma_f32_16x16x32_bf16(a0, B[0][0], c0, 0, 0, 0);
        c1 = __builtin_amdgcn_mfma_f32_16x16x32_bf16(a0, B[1][0], c1, 0, 0, 0);
        c2 = __builtin_amdgcn_mfma_f32_16x16x32_bf16(a0, B[2][0], c2, 0, 0, 0);
        c3 = __builtin_amdgcn_mfma_f32_16x16x32_bf16(a0, B[3][0], c3, 0, 0, 0);
        c0 = __builtin_amdgcn_mfma_f32_16x16x32_bf16(a1, B[0][1], c0, 0, 0, 0);
        c1 = __builtin_amdgcn_mfma_f32_16x16x32_bf16(a1, B[1][1], c1, 0, 0, 0);
        c2 = __builtin_amdgcn_mfma_f32_16x16x32_bf16(a1, B[2][1], c2, 0, 0, 0);
        c3 = __builtin_amdgcn_mfma_f32_16x16x32_bf16(a1, B[3][1], c3, 0, 0, 0);
        float px[4] = {0.f, 0.f, 0.f, 0.f}, py[4] = {0.f, 0.f, 0.f, 0.f};
#pragma unroll
        for (int ct = 0; ct < 4; ++ct) {
            f32x4 c = (ct == 0) ? c0 : (ct == 1) ? c1 : (ct == 2) ? c2 : c3;
#pragma unroll
            for (int r = 0; r < 4; ++r) {
                float o = c[r] + bv[ct];
                o = o > 0.f ? o : expm1f(o);               // ELU
                px[r] = fmaf(o, w3v[ct].x, px[r]);
                py[r] = fmaf(o, w3v[ct].y, py[r]);
            }
        }
#pragma unroll
        for (int mk = 1; mk < 16; mk <<= 1) {
#pragma unroll
            for (int r = 0; r < 4; ++r) {
                px[r] += __shfl_xor(px[r], mk);
                py[r] += __shfl_xor(py[r], mk);
            }
        }
        if (m == 0) {
#pragma unroll
            for (int r = 0; r < 4; ++r) {
                red[wv][quad * 4 + r][0] = px[r];
                red[wv][quad * 4 + r][1] = py[r];
            }
        }
        __syncthreads();
        if (t < 32) {
            int row = t >> 1, xy = t & 1;
            float s = red[0][row][xy] + red[1][row][xy]
                    + red[2][row][xy] + red[3][row][xy];
            ((float*)(xw3 + (rbase + row)))[xy] = s * dinv[rbase + row];
        }
        __syncthreads();
    }
}

// ---------------- GCN2 aggregate: out = dinv[d]*sum_s xw3[s] + b3 -----------
__global__ __launch_bounds__(256) void k_agg3(const int* __restrict__ rowptr,
        const int* __restrict__ col, const float2* __restrict__ xw3,
        const float* __restrict__ dinv, const float* __restrict__ b3,
        float* __restrict__ out) {
    int t = threadIdx.x;
    int lane = t & 63;
    int g = lane >> 2, s = lane & 3;
    int d = blockIdx.x * 64 + (t >> 6) * 16 + g;
    if (d >= N_NODES) return;
    int e0 = rowptr[d], e1 = rowptr[d + 1];
    float a0 = 0.f, a1 = 0.f;
    for (int e = e0 + s; e < e1; e += 4) {
        float2 v = xw3[col[e]];
        a0 += v.x; a1 += v.y;
    }
    a0 += __shfl_xor(a0, 1); a1 += __shfl_xor(a1, 1);
    a0 += __shfl_xor(a0, 2); a1 += __shfl_xor(a1, 2);
    if (s == 0) {
        float di = dinv[d];
        out[d * 2 + 0] = fmaf(a0, di, b3[0]);
        out[d * 2 + 1] = fmaf(a1, di, b3[1]);
    }
}

// ---------------- launch ----------------

extern "C" void kernel_launch(void* const* d_in, const int* in_sizes, int n_in,
                              void* d_out, int out_size, void* d_ws, size_t ws_size,
                              hipStream_t stream) {
    const float* x       = (const float*)d_in[0];
    const int*   ei      = (const int*)d_in[1];
    const float* W1      = (const float*)d_in[2];
    const float* b1      = (const float*)d_in[3];
    const float* W2      = (const float*)d_in[4];
    const float* att_src = (const float*)d_in[5];
    const float* att_dst = (const float*)d_in[6];
    const float* b2      = (const float*)d_in[7];
    const float* W3      = (const float*)d_in[8];
    const float* b3      = (const float*)d_in[9];
    float* out = (float*)d_out;
    (void)in_sizes; (void)n_in; (void)out_size; (void)ws_size;

    char* ws = (char*)d_ws;
    size_t off = 0;
    auto alloc = [&](size_t bytes) -> void* {
        void* p = ws + off;
        off = (off + bytes + 255) & ~(size_t)255;
        return p;
    };
    int*    rowptr = (int*)alloc((N_NODES + 1) * sizeof(int));
    int*    cnt    = (int*)alloc(N_NODES * sizeof(int));
    int*    bsum   = (int*)alloc(NSB * sizeof(int));
    int*    col    = (int*)alloc((size_t)E2 * sizeof(int));
    float*  dinv   = (float*)alloc(N_NODES * sizeof(float));
    unsigned short* W2t  = (unsigned short*)alloc(64 * 256 * sizeof(unsigned short));
    unsigned short* wsdt = (unsigned short*)alloc(16 * 64 * sizeof(unsigned short));
    unsigned short* W1t  = (unsigned short*)alloc(64 * 128 * sizeof(unsigned short));
    unsigned short* xw1b = (unsigned short*)alloc((size_t)N_NODES * HID * sizeof(unsigned short));
    unsigned short* h1b  = (unsigned short*)alloc((size_t)N_NODES * HID * sizeof(unsigned short));
    float*  a_s    = (float*)alloc((size_t)N_NODES * HEADS * sizeof(float));
    float*  a_d    = (float*)alloc((size_t)N_NODES * HEADS * sizeof(float));
    unsigned short* ub   = (unsigned short*)alloc((size_t)N_NODES * HH * sizeof(unsigned short));
    float2* xw3    = (float2*)alloc((size_t)N_NODES * sizeof(float2));
    // hp16 (20 MB) + rank16 (3.2 MB) ALIAS the front of ub (51.2 MB):
    // both dead after k_fill; ub first written by k_agg2u (later in stream).
    unsigned short* hp16   = ub;
    unsigned short* rank16 = ub + (size_t)NHB * BINS;

    k_prep<<<98, 256, 0, stream>>>(W2, W1, att_src, att_dst, W2t, wsdt, W1t);
    k_hist<<<NHB, HTH, 0, stream>>>(ei, hp16, rank16);
    k_scan1<<<NSB, 256, 0, stream>>>(hp16, cnt, bsum);
    k_scan3<<<NSB, 256, 0, stream>>>(cnt, bsum, rowptr, dinv, col);
    k_gemm1d<<<NGEMM1, 256, 0, stream>>>(x, W1t, dinv, xw1b);
    k_fill<<<NFC, 256, 0, stream>>>(ei, rowptr, hp16, rank16, col);

    k_agg1a<<<(N_NODES + 3) / 4, 256, 0, stream>>>(rowptr, col, xw1b, dinv, b1,
                                                   wsdt, h1b, a_s, a_d);
    k_agg2u<<<(N_NODES + 3) / 4, 256, 0, stream>>>(rowptr, col, h1b, a_s, a_d, ub);
    k_gemm3m<<<(N_NODES / 16) / RT, 256, 0, stream>>>(ub, W2t, b2, W3, dinv, xw3);
    k_agg3<<<(N_NODES + 63) / 64, 256, 0, stream>>>(rowptr, col, xw3, dinv, b3, out);
}

// Round 15
// 363.435 us; speedup vs baseline: 1.0352x; 1.0352x over previous
//
#include <hip/hip_runtime.h>
#include <math.h>

// Problem constants (from reference)
#define N_NODES 100000
#define N_EDGES 1600000
#define E2      (N_NODES + N_EDGES)   // edges incl. self-loops = 1,700,000
#define IN_C    128
#define HID     64
#define HEADS   4
#define HH      256                    // HEADS*HID
#define OUT_C   2
#define NEG_SLOPE 0.2f

#define SB   1024                      // elements per scan block
#define NSB  ((N_NODES + SB - 1) / SB) // 98
#define NRANGE 4                       // dst ranges (bands of 25000 nodes)
#define RDIV   25000
#define BINS   RDIV                    // histogram bins per band (u16)
#define BINW   (BINS / 2)              // packed u32 words in LDS = 12500 (50KB)
#define NBK    100                     // chunks per band (hist blocks)
#define CHUNK  (N_EDGES / NBK)         // 16000 edges per chunk
#define C4     (CHUNK / 4)             // 4000 int4 per chunk
#define HTH    1024                    // hist block size (occupancy lever)
#define CITER4 ((C4 + HTH - 1) / HTH)  // 4
#define NHB    (NRANGE * NBK)          // 400 hist blocks
#define NFC    (N_EDGES / 256)         // 6250 fill blocks (unbanded)
#define RT     10                      // row-tiles (16 rows) per gemm3m block
#define NT1    6250                    // gemm1 row-tiles (16 rows each)
#define NGEMM1 ((NT1 + 3) / 4)         // 1563 gemm1 blocks (4 tiles each)

typedef __attribute__((ext_vector_type(8))) short bf16x8;
typedef __attribute__((ext_vector_type(4))) float f32x4;

__device__ __forceinline__ float bf2f(unsigned short u) {
    return __uint_as_float(((unsigned)u) << 16);
}
__device__ __forceinline__ unsigned short f2bf(float f) {
    unsigned u = __float_as_uint(f);
    u += 0x7fffu + ((u >> 16) & 1u);   // RNE
    return (unsigned short)(u >> 16);
}

// ---------------- history ----------------
// r1: global-atomic hist 74us wall. r3: LDS-cursor fill 90us. r5: banded
// fill 8x re-read. r6: fill+gemm1 L2 thrash. r7/r8 regressions reverted r9.
// r12 = 363us BEST (agg1a unroll4 + dinv-fold, hist@1024th, merged agg2u).
// r13 (+11: scan1-atomic + agg2u split/unroll8) and r14 (+13: agg1a
// clamped loads) both regressed — every micro-edit to the latency-bound
// gather loops measures flat-to-negative (VGPR pinned at 16 throughout;
// compiler never deepens the pipeline). r15 = EXACT r12 revert, no
// experimental edits bundled (pure re-anchor).
// WS: hp16 (20 MB) + rank16 (3.2 MB) ALIAS the front of ub — both die
// after k_fill; ub is first written by k_agg2u (later in stream order).

// prep: b<64: W2t transpose; b in [64,66): wsdt; b in [66,98): W1t.
__global__ __launch_bounds__(256) void k_prep(const float* __restrict__ W2,
        const float* __restrict__ W1,
        const float* __restrict__ att_src, const float* __restrict__ att_dst,
        unsigned short* __restrict__ W2t, unsigned short* __restrict__ wsdt,
        unsigned short* __restrict__ W1t) {
    int b = blockIdx.x, t = threadIdx.x;
    if (b < 64) {                       // W2t[n*64+k] = bf16(W2[k][n])
        int g = b * 256 + t;            // g = k*256 + n
        int k = g >> 8, n = g & 255;
        W2t[n * 64 + k] = f2bf(W2[g]);
        return;
    }
    if (b < 66) {                       // wsdt[o*64+k], cols 8..15 zeroed
        int g = (b - 64) * 256 + t;     // 0..511
        wsdt[512 + g] = 0;
        int k = g >> 3, o = g & 7;
        int h = o & 3;
        const float* att = (o < 4) ? att_src : att_dst;
        float acc = 0.f;
        const float* wrow = W2 + (size_t)k * HH + h * 64;
        const float* arow = att + h * 64;
        for (int c = 0; c < 64; ++c) acc = fmaf(wrow[c], arow[c], acc);
        wsdt[o * 64 + k] = f2bf(acc);
        return;
    }
    // W1t[n*128+k] = bf16(W1[k][n])
    int g = (b - 66) * 256 + t;         // 0..8191, g = k*64 + n
    int k = g >> 6, n = g & 63;
    W1t[n * 128 + k] = f2bf(W1[g]);
}

// Banded-LDS hist, int4 loads, PACKED u16 bins (2 per u32; counts < 16000
// so neither half can carry). b = k*4 + r: the 4 band-copies of a chunk are
// dispatch-adjacent (round-robin XCDs) so dst bytes are L3-served after the
// first miss. 1024 threads/block: 2 blocks/CU = 32 waves/CU (HW max).
__global__ __launch_bounds__(HTH) void k_hist(const int* __restrict__ ei,
        unsigned short* __restrict__ hp16, unsigned short* __restrict__ rank16) {
    __shared__ unsigned int hh[BINW];   // 50 KB, 2 bins/word
    int b = blockIdx.x, t = threadIdx.x;
    int r = b & 3, k = b >> 2;          // band, chunk
    for (int i = t; i < BINW; i += HTH) hh[i] = 0u;
    __syncthreads();
    const int4* dp4 = (const int4*)(ei + N_EDGES + (size_t)k * CHUNK);
    unsigned short* rp = rank16 + (size_t)k * CHUNK;
    int lo = r * RDIV;
#pragma unroll 2
    for (int it = 0; it < CITER4; ++it) {
        int i4 = it * HTH + t;
        if (i4 < C4) {
            int4 v = dp4[i4];
            int base = i4 * 4;
            int d0 = v.x - lo, d1 = v.y - lo, d2 = v.z - lo, d3 = v.w - lo;
            if ((unsigned)d0 < (unsigned)RDIV) {
                unsigned sh = (d0 & 1) * 16;
                unsigned old = atomicAdd(&hh[d0 >> 1], 1u << sh);
                rp[base + 0] = (unsigned short)(old >> sh);
            }
            if ((unsigned)d1 < (unsigned)RDIV) {
                unsigned sh = (d1 & 1) * 16;
                unsigned old = atomicAdd(&hh[d1 >> 1], 1u << sh);
                rp[base + 1] = (unsigned short)(old >> sh);
            }
            if ((unsigned)d2 < (unsigned)RDIV) {
                unsigned sh = (d2 & 1) * 16;
                unsigned old = atomicAdd(&hh[d2 >> 1], 1u << sh);
                rp[base + 2] = (unsigned short)(old >> sh);
            }
            if ((unsigned)d3 < (unsigned)RDIV) {
                unsigned sh = (d3 & 1) * 16;
                unsigned old = atomicAdd(&hh[d3 >> 1], 1u << sh);
                rp[base + 3] = (unsigned short)(old >> sh);
            }
        }
    }
    __syncthreads();
    // table writeout: packed u32 layout == consecutive u16 bins (LE)
    unsigned* hp = (unsigned*)(hp16 + (size_t)(r * NBK + k) * BINS);
    for (int i = t; i < BINW; i += HTH) hp[i] = hh[i];
}

// scan1: cnt[i] = sum_k h[r][k][bin]; converts hp16 IN PLACE to exclusive
// prefixes over k; emits per-block degree sums -> bsum.
__global__ __launch_bounds__(256) void k_scan1(unsigned short* __restrict__ hp16,
        int* __restrict__ cnt, int* __restrict__ bsum) {
    int b = blockIdx.x, t = threadIdx.x;
    int s = 0;
#pragma unroll
    for (int u = 0; u < 4; ++u) {
        int i = b * SB + u * 256 + t;
        if (i < N_NODES) {
            int r = i / RDIV, bin = i - r * RDIV;
            unsigned short* p = hp16 + (size_t)r * NBK * BINS + bin;
            unsigned acc = 0;
            for (int k = 0; k < NBK; ++k) {
                unsigned short hv = p[(size_t)k * BINS];
                p[(size_t)k * BINS] = (unsigned short)acc;
                acc += hv;
            }
            cnt[i] = (int)acc;
            s += (int)acc + 1;           // +1 self-loop
        }
    }
#pragma unroll
    for (int off = 1; off < 64; off <<= 1) s += __shfl_xor(s, off);
    __shared__ int wsum[4];
    int lane = t & 63, wv = t >> 6;
    if (lane == 0) wsum[wv] = s;
    __syncthreads();
    if (t == 0) bsum[b] = (wsum[0] + wsum[1]) + (wsum[2] + wsum[3]);
}

// scan3: block b computes prefix over bsum[0..b) itself, scans its chunk
// (deg = cnt+1), writes rowptr + dinv, pre-places self-loops at slot 0.
__global__ __launch_bounds__(256) void k_scan3(const int* __restrict__ cnt,
        const int* __restrict__ bsum, int* __restrict__ rowptr,
        float* __restrict__ dinv, int* __restrict__ col) {
    int b = blockIdx.x, t = threadIdx.x;
    int lane = t & 63, wv = t >> 6;
    __shared__ int wred[4];
    {
        int v = (t < b) ? bsum[t] : 0;   // b <= 98 <= 256
#pragma unroll
        for (int off = 1; off < 64; off <<= 1) v += __shfl_xor(v, off);
        if (lane == 0) wred[wv] = v;
    }
    __syncthreads();
    int pre = (wred[0] + wred[1]) + (wred[2] + wred[3]);
    __syncthreads();

    int i = b * SB + t * 4;
    int c0 = 0, c1 = 0, c2 = 0, c3 = 0;
    if (i + 3 < N_NODES) {
        int4 v = *(const int4*)(cnt + i);
        c0 = v.x; c1 = v.y; c2 = v.z; c3 = v.w;
    } else if (i < N_NODES) {
        c0 = cnt[i];
        if (i + 1 < N_NODES) c1 = cnt[i + 1];
        if (i + 2 < N_NODES) c2 = cnt[i + 2];
    }
    int n0 = (i < N_NODES), n1 = (i + 1 < N_NODES),
        n2 = (i + 2 < N_NODES), n3 = (i + 3 < N_NODES);
    int d0 = c0 + n0, d1 = c1 + n1, d2 = c2 + n2, d3 = c3 + n3;  // degrees
    int s = (d0 + d1) + (d2 + d3);
    int inc = s;
#pragma unroll
    for (int off = 1; off < 64; off <<= 1) {
        int u = __shfl_up(inc, off);
        if (lane >= off) inc += u;
    }
    __shared__ int wtot[4];
    if (lane == 63) wtot[wv] = inc;
    __syncthreads();
    int base = pre + (inc - s);
    for (int w = 0; w < wv; ++w) base += wtot[w];
    if (n0) { rowptr[i]     = base;                dinv[i]     = rsqrtf((float)d0); col[base] = i; }
    if (n1) { rowptr[i + 1] = base + d0;           dinv[i + 1] = rsqrtf((float)d1); col[base + d0] = i + 1; }
    if (n2) { rowptr[i + 2] = base + d0 + d1;      dinv[i + 2] = rsqrtf((float)d2); col[base + d0 + d1] = i + 2; }
    if (n3) { rowptr[i + 3] = base + d0 + d1 + d2; dinv[i + 3] = rsqrtf((float)d3); col[base + d0 + d1 + d2] = i + 3; }
    if (b == 0 && t == 0) rowptr[N_NODES] = E2;
}

// gemm1d: xw1b = bf16(dinv[row] * (x @ W1)) — dinv FOLDED (r0 numerics).
__global__ __launch_bounds__(256) void k_gemm1d(const float* __restrict__ x,
        const unsigned short* __restrict__ W1t, const float* __restrict__ dinv,
        unsigned short* __restrict__ xw1b) {
    int t = threadIdx.x;
    int lane = t & 63, wv = t >> 6;
    int m = lane & 15, quad = lane >> 4;
    bf16x8 B[4][4];
#pragma unroll
    for (int ct = 0; ct < 4; ++ct)
#pragma unroll
        for (int ks = 0; ks < 4; ++ks)
            B[ct][ks] = *(const bf16x8*)(W1t + (size_t)(ct * 16 + m) * IN_C
                                         + ks * 32 + quad * 8);
    int tile = blockIdx.x * 4 + wv;
    if (tile >= NT1) return;
    int rbase = tile * 16;
    const float* xp = x + (size_t)(rbase + m) * IN_C + quad * 8;
    f32x4 c0 = {0.f, 0.f, 0.f, 0.f}, c1 = c0, c2 = c0, c3 = c0;
#pragma unroll
    for (int ks = 0; ks < 4; ++ks) {
        float4 f0 = *(const float4*)(xp + ks * 32);
        float4 f1 = *(const float4*)(xp + ks * 32 + 4);
        bf16x8 a;
        a[0] = (short)f2bf(f0.x); a[1] = (short)f2bf(f0.y);
        a[2] = (short)f2bf(f0.z); a[3] = (short)f2bf(f0.w);
        a[4] = (short)f2bf(f1.x); a[5] = (short)f2bf(f1.y);
        a[6] = (short)f2bf(f1.z); a[7] = (short)f2bf(f1.w);
        c0 = __builtin_amdgcn_mfma_f32_16x16x32_bf16(a, B[0][ks], c0, 0, 0, 0);
        c1 = __builtin_amdgcn_mfma_f32_16x16x32_bf16(a, B[1][ks], c1, 0, 0, 0);
        c2 = __builtin_amdgcn_mfma_f32_16x16x32_bf16(a, B[2][ks], c2, 0, 0, 0);
        c3 = __builtin_amdgcn_mfma_f32_16x16x32_bf16(a, B[3][ks], c3, 0, 0, 0);
    }
    int row0 = rbase + quad * 4;
    float4 dv = *(const float4*)(dinv + row0);   // 16B-aligned (row0 % 4 == 0)
    float dr[4] = {dv.x, dv.y, dv.z, dv.w};
#pragma unroll
    for (int ct = 0; ct < 4; ++ct) {
        f32x4 c = (ct == 0) ? c0 : (ct == 1) ? c1 : (ct == 2) ? c2 : c3;
        unsigned short* p = xw1b + (size_t)row0 * HID + ct * 16 + m;
#pragma unroll
        for (int r = 0; r < 4; ++r) p[(size_t)r * HID] = f2bf(c[r] * dr[r]);
    }
}

// fill: unbanded single-pass scatter, UNFUSED.
// pos = rowptr[d] + 1 + prefix[band][chunk][bin] + rank16[i].
__global__ void k_fill(const int* __restrict__ ei, const int* __restrict__ rowptr,
        const unsigned short* __restrict__ hp16,
        const unsigned short* __restrict__ rank16, int* __restrict__ col) {
    int i = blockIdx.x * 256 + threadIdx.x;  // NFC*256 == N_EDGES exactly
    int d = ei[N_EDGES + i];
    int s = ei[i];
    int r = d / RDIV;
    int bin = d - r * RDIV;
    int k = i / CHUNK;
    unsigned pos = (unsigned)rowptr[d] + 1u
                 + (unsigned)hp16[(size_t)(r * NBK + k) * BINS + bin]
                 + (unsigned)rank16[i];
    col[pos] = s;                           // slot 0 = self-loop
}

// ------- GCN1 aggregate + FUSED attention logits -------
// xw1b already carries dinv[src]: inner loop = shfl + ushort4 load + 4 add.
__global__ __launch_bounds__(256) void k_agg1a(const int* __restrict__ rowptr,
        const int* __restrict__ col, const unsigned short* __restrict__ xw1b,
        const float* __restrict__ dinv, const float* __restrict__ b1,
        const unsigned short* __restrict__ wsdt,
        unsigned short* __restrict__ h1b,
        float* __restrict__ a_s, float* __restrict__ a_d) {
    int t = threadIdx.x;
    int lane = t & 63;
    int d = blockIdx.x * 4 + (t >> 6);
    if (d >= N_NODES) return;
    int start = rowptr[d], end = rowptr[d + 1];
    int sub = lane >> 4;       // which of 4 edges in a group
    int cpos = lane & 15;      // channel quad (4 bf16)
    float4 acc = make_float4(0.f, 0.f, 0.f, 0.f);
    for (int base = start; base < end; base += 64) {
        int cnt = min(64, end - base);
        int sl = (base + lane < end) ? col[base + lane] : 0;
#pragma unroll 4
        for (int j = 0; j < cnt; j += 4) {
            int idx = j + sub;
            int sj = __shfl(sl, idx);
            if (idx < cnt) {
                ushort4 v = ((const ushort4*)(xw1b + (size_t)sj * HID))[cpos];
                acc.x += bf2f(v.x);
                acc.y += bf2f(v.y);
                acc.z += bf2f(v.z);
                acc.w += bf2f(v.w);
            }
        }
    }
    acc.x += __shfl_xor(acc.x, 16); acc.y += __shfl_xor(acc.y, 16);
    acc.z += __shfl_xor(acc.z, 16); acc.w += __shfl_xor(acc.w, 16);
    acc.x += __shfl_xor(acc.x, 32); acc.y += __shfl_xor(acc.y, 32);
    acc.z += __shfl_xor(acc.z, 32); acc.w += __shfl_xor(acc.w, 32);
    // every lane now holds the fully-reduced quad for channels cpos*4..+3
    float di = dinv[d];
    float4 b = ((const float4*)b1)[cpos];
    float h0 = fmaf(acc.x, di, b.x); h0 = h0 > 0.f ? h0 : 0.f;
    float h1 = fmaf(acc.y, di, b.y); h1 = h1 > 0.f ? h1 : 0.f;
    float h2 = fmaf(acc.z, di, b.z); h2 = h2 > 0.f ? h2 : 0.f;
    float h3 = fmaf(acc.w, di, b.w); h3 = h3 > 0.f ? h3 : 0.f;
    ushort4 o = make_ushort4(f2bf(h0), f2bf(h1), f2bf(h2), f2bf(h3));
    if (lane < 16)
        ((ushort4*)(h1b + (size_t)d * HID))[cpos] = o;
    // attention dots on bf16-rounded values (== old k_attn's inputs)
    float r0 = bf2f(o.x), r1 = bf2f(o.y), r2 = bf2f(o.z), r3 = bf2f(o.w);
    int hsel = lane >> 4;                        // head 0..3
    ushort4 ws = ((const ushort4*)(wsdt + hsel * 64))[cpos];
    ushort4 wd = ((const ushort4*)(wsdt + (hsel + 4) * 64))[cpos];
    float ps = r0 * bf2f(ws.x) + r1 * bf2f(ws.y)
             + r2 * bf2f(ws.z) + r3 * bf2f(ws.w);
    float pd = r0 * bf2f(wd.x) + r1 * bf2f(wd.y)
             + r2 * bf2f(wd.z) + r3 * bf2f(wd.w);
#pragma unroll
    for (int mk = 1; mk < 16; mk <<= 1) {
        ps += __shfl_xor(ps, mk);
        pd += __shfl_xor(pd, mk);
    }
    if (cpos == 0) {
        a_s[d * 4 + hsel] = ps;
        a_d[d * 4 + hsel] = pd;
    }
}

// ---------------- GAT aggregate on h1 (agg commutes with W2) ----------------
// r6/r12 form: merged single dispatch, 1 edge/iter, unroll 4.
__global__ __launch_bounds__(256) void k_agg2u(const int* __restrict__ rowptr,
        const int* __restrict__ col, const unsigned short* __restrict__ h1b,
        const float* __restrict__ a_s, const float* __restrict__ a_d,
        unsigned short* __restrict__ ub) {
    __shared__ int   ss[4][64];      // 1 KB
    __shared__ float sp[4][64][4];   // 4 KB
    int t = threadIdx.x;
    int lane = t & 63, wv = t >> 6;
    int d = blockIdx.x * 4 + wv;
    if (d >= N_NODES) return;
    const float4* as4 = (const float4*)a_s;
    float4 adv = ((const float4*)a_d)[d];
    int start = rowptr[d], end = rowptr[d + 1];

    float den0 = 0.f, den1 = 0.f, den2 = 0.f, den3 = 0.f;
    float acc0 = 0.f, acc1 = 0.f, acc2 = 0.f, acc3 = 0.f;
    for (int base = start; base < end; base += 64) {
        int cnt = min(64, end - base);
        float p0 = 0.f, p1 = 0.f, p2 = 0.f, p3 = 0.f;
        int s = 0;
        if (lane < cnt) {
            s = col[base + lane];
            float4 av = as4[s];
            float v;
            v = av.x + adv.x; v = v > 0.f ? v : NEG_SLOPE * v; p0 = __expf(v);
            v = av.y + adv.y; v = v > 0.f ? v : NEG_SLOPE * v; p1 = __expf(v);
            v = av.z + adv.z; v = v > 0.f ? v : NEG_SLOPE * v; p2 = __expf(v);
            v = av.w + adv.w; v = v > 0.f ? v : NEG_SLOPE * v; p3 = __expf(v);
            den0 += p0; den1 += p1; den2 += p2; den3 += p3;
        }
        ss[wv][lane] = s;                                  // wave-private LDS
        ((float4*)sp[wv])[lane] = make_float4(p0, p1, p2, p3);
#pragma unroll 4
        for (int j = 0; j < cnt; ++j) {
            int sj = ss[wv][j];                            // broadcast read
            float4 pj = ((const float4*)sp[wv])[j];        // broadcast read
            float v = bf2f(h1b[(unsigned)sj * 64u + (unsigned)lane]); // 2B/lane
            acc0 = fmaf(pj.x, v, acc0);
            acc1 = fmaf(pj.y, v, acc1);
            acc2 = fmaf(pj.z, v, acc2);
            acc3 = fmaf(pj.w, v, acc3);
        }
    }
#pragma unroll
    for (int mk = 1; mk < 64; mk <<= 1) {
        den0 += __shfl_xor(den0, mk);
        den1 += __shfl_xor(den1, mk);
        den2 += __shfl_xor(den2, mk);
        den3 += __shfl_xor(den3, mk);
    }
    float u0 = acc0 / (den0 + 1e-16f);
    float u1 = acc1 / (den1 + 1e-16f);
    float u2 = acc2 / (den2 + 1e-16f);
    float u3 = acc3 / (den3 + 1e-16f);
    unsigned short* up = ub + (size_t)d * HH;
    up[lane]       = f2bf(u0);
    up[64 + lane]  = f2bf(u1);
    up[128 + lane] = f2bf(u2);
    up[192 + lane] = f2bf(u3);
}

// ---------------- W2-apply + b2 + ELU + W3 + dinv, via MFMA -----------------
__global__ __launch_bounds__(256) void k_gemm3m(const unsigned short* __restrict__ ub,
        const unsigned short* __restrict__ W2t, const float* __restrict__ b2,
        const float* __restrict__ W3, const float* __restrict__ dinv,
        float2* __restrict__ xw3) {
    int t = threadIdx.x;
    int lane = t & 63, wv = t >> 6;
    int m = lane & 15, quad = lane >> 4;
    int nb = wv * 64 + m;            // lane's base output column (head = wv)
    bf16x8 B[4][2];
#pragma unroll
    for (int ct = 0; ct < 4; ++ct)
#pragma unroll
        for (int ks = 0; ks < 2; ++ks)
            B[ct][ks] = *(const bf16x8*)(W2t + (size_t)(nb + ct * 16) * 64
                                         + ks * 32 + quad * 8);
    float bv[4]; float2 w3v[4];
#pragma unroll
    for (int ct = 0; ct < 4; ++ct) {
        int n = nb + ct * 16;
        bv[ct] = b2[n];
        w3v[ct] = ((const float2*)W3)[n];
    }
    __shared__ float red[4][16][2];  // [wave][row][xy]
    int r0 = blockIdx.x * (RT * 16);
    for (int tile = 0; tile < RT; ++tile) {
        int rbase = r0 + tile * 16;
        const unsigned short* ap = ub + (size_t)(rbase + m) * HH + wv * 64 + quad * 8;
        bf16x8 a0 = *(const bf16x8*)(ap);
        bf16x8 a1 = *(const bf16x8*)(ap + 32);
        f32x4 c0 = {0.f, 0.f, 0.f, 0.f}, c1 = c0, c2 = c0, c3 = c0;
        c0 = __builtin_amdgcn_mfma_f32_16x16x32_bf16(a0, B[0][0], c0, 0, 0, 0);
        c1 = __builtin_amdgcn_mfma_f32_16x16x32_bf16(a0, B[1][0], c1, 0, 0, 0);
        c2 = __builtin_amdgcn_mfma_f32_16x16x32_bf16(a0, B[2][0], c2, 0, 0, 0);
        c3 = __builtin_amdgcn_mfma_f32_16x16x32_bf16(a0, B[3][0], c3, 0, 0, 0);
        c0 = __builtin_amdgcn_mfma_f32_16x16x32_bf16(a1, B[0][1], c0, 0, 0, 0);
        c1 = __builtin_amdgcn_mfma_f32_16x16x32_bf16(a1, B[1][1], c1, 0, 0, 0);
        c2 = __builtin_amdgcn_mfma_f32_16x16x32_bf16(a1, B[2][1], c2, 0, 0, 0);
        c3 = __builtin_amdgcn_mfma_f32_16x16x32_bf16(a1, B[3][1], c3, 0, 0, 0);
        float px[4] = {0.f, 0.f, 0.f, 0.f}, py[4] = {0.f, 0.f, 0.f, 0.f};
#pragma unroll
        for (int ct = 0; ct < 4; ++ct) {
            f32x4 c = (ct == 0) ? c0 : (ct == 1) ? c1 : (ct == 2) ? c2 : c3;
#pragma unroll
            for (int r = 0; r < 4; ++r) {
                float o = c[r] + bv[ct];
                o = o > 0.f ? o : expm1f(o);               // ELU
                px[r] = fmaf(o, w3v[ct].x, px[r]);
                py[r] = fmaf(o, w3v[ct].y, py[r]);
            }
        }
#pragma unroll
        for (int mk = 1; mk < 16; mk <<= 1) {
#pragma unroll
            for (int r = 0; r < 4; ++r) {
                px[r] += __shfl_xor(px[r], mk);
                py[r] += __shfl_xor(py[r], mk);
            }
        }
        if (m == 0) {
#pragma unroll
            for (int r = 0; r < 4; ++r) {
                red[wv][quad * 4 + r][0] = px[r];
                red[wv][quad * 4 + r][1] = py[r];
            }
        }
        __syncthreads();
        if (t < 32) {
            int row = t >> 1, xy = t & 1;
            float s = red[0][row][xy] + red[1][row][xy]
                    + red[2][row][xy] + red[3][row][xy];
            ((float*)(xw3 + (rbase + row)))[xy] = s * dinv[rbase + row];
        }
        __syncthreads();
    }
}

// ---------------- GCN2 aggregate: out = dinv[d]*sum_s xw3[s] + b3 -----------
__global__ __launch_bounds__(256) void k_agg3(const int* __restrict__ rowptr,
        const int* __restrict__ col, const float2* __restrict__ xw3,
        const float* __restrict__ dinv, const float* __restrict__ b3,
        float* __restrict__ out) {
    int t = threadIdx.x;
    int lane = t & 63;
    int g = lane >> 2, s = lane & 3;
    int d = blockIdx.x * 64 + (t >> 6) * 16 + g;
    if (d >= N_NODES) return;
    int e0 = rowptr[d], e1 = rowptr[d + 1];
    float a0 = 0.f, a1 = 0.f;
    for (int e = e0 + s; e < e1; e += 4) {
        float2 v = xw3[col[e]];
        a0 += v.x; a1 += v.y;
    }
    a0 += __shfl_xor(a0, 1); a1 += __shfl_xor(a1, 1);
    a0 += __shfl_xor(a0, 2); a1 += __shfl_xor(a1, 2);
    if (s == 0) {
        float di = dinv[d];
        out[d * 2 + 0] = fmaf(a0, di, b3[0]);
        out[d * 2 + 1] = fmaf(a1, di, b3[1]);
    }
}

// ---------------- launch ----------------

extern "C" void kernel_launch(void* const* d_in, const int* in_sizes, int n_in,
                              void* d_out, int out_size, void* d_ws, size_t ws_size,
                              hipStream_t stream) {
    const float* x       = (const float*)d_in[0];
    const int*   ei      = (const int*)d_in[1];
    const float* W1      = (const float*)d_in[2];
    const float* b1      = (const float*)d_in[3];
    const float* W2      = (const float*)d_in[4];
    const float* att_src = (const float*)d_in[5];
    const float* att_dst = (const float*)d_in[6];
    const float* b2      = (const float*)d_in[7];
    const float* W3      = (const float*)d_in[8];
    const float* b3      = (const float*)d_in[9];
    float* out = (float*)d_out;
    (void)in_sizes; (void)n_in; (void)out_size; (void)ws_size;

    char* ws = (char*)d_ws;
    size_t off = 0;
    auto alloc = [&](size_t bytes) -> void* {
        void* p = ws + off;
        off = (off + bytes + 255) & ~(size_t)255;
        return p;
    };
    int*    rowptr = (int*)alloc((N_NODES + 1) * sizeof(int));
    int*    cnt    = (int*)alloc(N_NODES * sizeof(int));
    int*    bsum   = (int*)alloc(NSB * sizeof(int));
    int*    col    = (int*)alloc((size_t)E2 * sizeof(int));
    float*  dinv   = (float*)alloc(N_NODES * sizeof(float));
    unsigned short* W2t  = (unsigned short*)alloc(64 * 256 * sizeof(unsigned short));
    unsigned short* wsdt = (unsigned short*)alloc(16 * 64 * sizeof(unsigned short));
    unsigned short* W1t  = (unsigned short*)alloc(64 * 128 * sizeof(unsigned short));
    unsigned short* xw1b = (unsigned short*)alloc((size_t)N_NODES * HID * sizeof(unsigned short));
    unsigned short* h1b  = (unsigned short*)alloc((size_t)N_NODES * HID * sizeof(unsigned short));
    float*  a_s    = (float*)alloc((size_t)N_NODES * HEADS * sizeof(float));
    float*  a_d    = (float*)alloc((size_t)N_NODES * HEADS * sizeof(float));
    unsigned short* ub   = (unsigned short*)alloc((size_t)N_NODES * HH * sizeof(unsigned short));
    float2* xw3    = (float2*)alloc((size_t)N_NODES * sizeof(float2));
    // hp16 (20 MB) + rank16 (3.2 MB) ALIAS the front of ub (51.2 MB):
    // both dead after k_fill; ub first written by k_agg2u (later in stream).
    unsigned short* hp16   = ub;
    unsigned short* rank16 = ub + (size_t)NHB * BINS;

    k_prep<<<98, 256, 0, stream>>>(W2, W1, att_src, att_dst, W2t, wsdt, W1t);
    k_hist<<<NHB, HTH, 0, stream>>>(ei, hp16, rank16);
    k_scan1<<<NSB, 256, 0, stream>>>(hp16, cnt, bsum);
    k_scan3<<<NSB, 256, 0, stream>>>(cnt, bsum, rowptr, dinv, col);
    k_gemm1d<<<NGEMM1, 256, 0, stream>>>(x, W1t, dinv, xw1b);
    k_fill<<<NFC, 256, 0, stream>>>(ei, rowptr, hp16, rank16, col);

    k_agg1a<<<(N_NODES + 3) / 4, 256, 0, stream>>>(rowptr, col, xw1b, dinv, b1,
                                                   wsdt, h1b, a_s, a_d);
    k_agg2u<<<(N_NODES + 3) / 4, 256, 0, stream>>>(rowptr, col, h1b, a_s, a_d, ub);
    k_gemm3m<<<(N_NODES / 16) / RT, 256, 0, stream>>>(ub, W2t, b2, W3, dinv, xw3);
    k_agg3<<<(N_NODES + 63) / 64, 256, 0, stream>>>(rowptr, col, xw3, dinv, b3, out);
}

// Round 16
// 358.027 us; speedup vs baseline: 1.0509x; 1.0151x over previous
//
#include <hip/hip_runtime.h>
#include <math.h>

// Problem constants (from reference)
#define N_NODES 100000
#define N_EDGES 1600000
#define E2      (N_NODES + N_EDGES)   // edges incl. self-loops = 1,700,000
#define IN_C    128
#define HID     64
#define HEADS   4
#define HH      256                    // HEADS*HID
#define OUT_C   2
#define NEG_SLOPE 0.2f

#define SB   1024                      // elements per scan block (bsum granule)
#define NSB  ((N_NODES + SB - 1) / SB) // 98
#define NSB1 ((N_NODES + 255) / 256)   // 391 scan1 blocks (r16: 4x threads)
#define NRANGE 4                       // dst ranges (bands of 25000 nodes)
#define RDIV   25000
#define BINS   RDIV                    // histogram bins per band (u16)
#define BINW   (BINS / 2)              // packed u32 words in LDS = 12500 (50KB)
#define NBK    100                     // chunks per band (hist blocks)
#define CHUNK  (N_EDGES / NBK)         // 16000 edges per chunk
#define C4     (CHUNK / 4)             // 4000 int4 per chunk
#define HTH    1024                    // hist block size (occupancy lever)
#define CITER4 ((C4 + HTH - 1) / HTH)  // 4
#define NHB    (NRANGE * NBK)          // 400 hist blocks
#define NFC    (N_EDGES / 256)         // 6250 fill blocks (unbanded)
#define RT     10                      // row-tiles (16 rows) per gemm3m block
#define NT1    6250                    // gemm1 row-tiles (16 rows each)
#define NGEMM1 ((NT1 + 3) / 4)         // 1563 gemm1 blocks (4 tiles each)

typedef __attribute__((ext_vector_type(8))) short bf16x8;
typedef __attribute__((ext_vector_type(4))) float f32x4;

__device__ __forceinline__ float bf2f(unsigned short u) {
    return __uint_as_float(((unsigned)u) << 16);
}
__device__ __forceinline__ unsigned short f2bf(float f) {
    unsigned u = __float_as_uint(f);
    u += 0x7fffu + ((u >> 16) & 1u);   // RNE
    return (unsigned short)(u >> 16);
}

// ---------------- history ----------------
// r12/r15 = 363.3/363.4us anchor (reproduces to 0.1us). r13 (+11) bundled
// scan1-4x with agg2u unroll8/split — attribution impossible. r14 (+13)
// clamped loads. r16 = r15 base + ONE change: the r13 scan1
// parallelization alone (1 node/thread, 391 blocks, block sums atomicAdd
// into bsum; prep zeroes bsum). scan1 was 98 blocks = 25K threads at
// ~1 block/CU walking 400-deep 50KB-strided u16 RMW chains — the prime
// hidden-time suspect below the profile window.
// WS: hp16 (20 MB) + rank16 (3.2 MB) ALIAS the front of ub — both die
// after k_fill; ub is first written by k_agg2u (later in stream order).

// prep: b<64: W2t transpose (+b==0 zeroes bsum); b in [64,66): wsdt;
// b in [66,98): W1t.
__global__ __launch_bounds__(256) void k_prep(const float* __restrict__ W2,
        const float* __restrict__ W1,
        const float* __restrict__ att_src, const float* __restrict__ att_dst,
        unsigned short* __restrict__ W2t, unsigned short* __restrict__ wsdt,
        unsigned short* __restrict__ W1t, int* __restrict__ bsum) {
    int b = blockIdx.x, t = threadIdx.x;
    if (b == 0 && t < NSB) bsum[t] = 0;   // for scan1's atomicAdd
    if (b < 64) {                       // W2t[n*64+k] = bf16(W2[k][n])
        int g = b * 256 + t;            // g = k*256 + n
        int k = g >> 8, n = g & 255;
        W2t[n * 64 + k] = f2bf(W2[g]);
        return;
    }
    if (b < 66) {                       // wsdt[o*64+k], cols 8..15 zeroed
        int g = (b - 64) * 256 + t;     // 0..511
        wsdt[512 + g] = 0;
        int k = g >> 3, o = g & 7;
        int h = o & 3;
        const float* att = (o < 4) ? att_src : att_dst;
        float acc = 0.f;
        const float* wrow = W2 + (size_t)k * HH + h * 64;
        const float* arow = att + h * 64;
        for (int c = 0; c < 64; ++c) acc = fmaf(wrow[c], arow[c], acc);
        wsdt[o * 64 + k] = f2bf(acc);
        return;
    }
    // W1t[n*128+k] = bf16(W1[k][n])
    int g = (b - 66) * 256 + t;         // 0..8191, g = k*64 + n
    int k = g >> 6, n = g & 63;
    W1t[n * 128 + k] = f2bf(W1[g]);
}

// Banded-LDS hist, int4 loads, PACKED u16 bins (2 per u32; counts < 16000
// so neither half can carry). b = k*4 + r: the 4 band-copies of a chunk are
// dispatch-adjacent (round-robin XCDs) so dst bytes are L3-served after the
// first miss. 1024 threads/block: 2 blocks/CU = 32 waves/CU (HW max).
__global__ __launch_bounds__(HTH) void k_hist(const int* __restrict__ ei,
        unsigned short* __restrict__ hp16, unsigned short* __restrict__ rank16) {
    __shared__ unsigned int hh[BINW];   // 50 KB, 2 bins/word
    int b = blockIdx.x, t = threadIdx.x;
    int r = b & 3, k = b >> 2;          // band, chunk
    for (int i = t; i < BINW; i += HTH) hh[i] = 0u;
    __syncthreads();
    const int4* dp4 = (const int4*)(ei + N_EDGES + (size_t)k * CHUNK);
    unsigned short* rp = rank16 + (size_t)k * CHUNK;
    int lo = r * RDIV;
#pragma unroll 2
    for (int it = 0; it < CITER4; ++it) {
        int i4 = it * HTH + t;
        if (i4 < C4) {
            int4 v = dp4[i4];
            int base = i4 * 4;
            int d0 = v.x - lo, d1 = v.y - lo, d2 = v.z - lo, d3 = v.w - lo;
            if ((unsigned)d0 < (unsigned)RDIV) {
                unsigned sh = (d0 & 1) * 16;
                unsigned old = atomicAdd(&hh[d0 >> 1], 1u << sh);
                rp[base + 0] = (unsigned short)(old >> sh);
            }
            if ((unsigned)d1 < (unsigned)RDIV) {
                unsigned sh = (d1 & 1) * 16;
                unsigned old = atomicAdd(&hh[d1 >> 1], 1u << sh);
                rp[base + 1] = (unsigned short)(old >> sh);
            }
            if ((unsigned)d2 < (unsigned)RDIV) {
                unsigned sh = (d2 & 1) * 16;
                unsigned old = atomicAdd(&hh[d2 >> 1], 1u << sh);
                rp[base + 2] = (unsigned short)(old >> sh);
            }
            if ((unsigned)d3 < (unsigned)RDIV) {
                unsigned sh = (d3 & 1) * 16;
                unsigned old = atomicAdd(&hh[d3 >> 1], 1u << sh);
                rp[base + 3] = (unsigned short)(old >> sh);
            }
        }
    }
    __syncthreads();
    // table writeout: packed u32 layout == consecutive u16 bins (LE)
    unsigned* hp = (unsigned*)(hp16 + (size_t)(r * NBK + k) * BINS);
    for (int i = t; i < BINW; i += HTH) hp[i] = hh[i];
}

// scan1 (r16): 1 node/thread, 391 blocks (was 98 blocks / 4 nodes per
// thread = 25K threads at ~1 block/CU). Converts hp16 IN PLACE to
// exclusive prefixes over k; cnt[i] = total; block sums atomicAdd into
// bsum[i/SB] (bsum zeroed by k_prep; integer sum is order-independent).
__global__ __launch_bounds__(256) void k_scan1(unsigned short* __restrict__ hp16,
        int* __restrict__ cnt, int* __restrict__ bsum) {
    int b = blockIdx.x, t = threadIdx.x;
    int i = b * 256 + t;
    int s = 0;
    if (i < N_NODES) {
        int r = i / RDIV, bin = i - r * RDIV;
        unsigned short* p = hp16 + (size_t)r * NBK * BINS + bin;
        unsigned acc = 0;
#pragma unroll 4
        for (int k = 0; k < NBK; ++k) {
            unsigned short hv = p[(size_t)k * BINS];
            p[(size_t)k * BINS] = (unsigned short)acc;
            acc += hv;
        }
        cnt[i] = (int)acc;
        s = (int)acc + 1;               // +1 self-loop
    }
#pragma unroll
    for (int off = 1; off < 64; off <<= 1) s += __shfl_xor(s, off);
    __shared__ int wsum[4];
    int lane = t & 63, wv = t >> 6;
    if (lane == 0) wsum[wv] = s;
    __syncthreads();
    if (t == 0)
        atomicAdd(&bsum[b >> 2], (wsum[0] + wsum[1]) + (wsum[2] + wsum[3]));
}

// scan3: block b computes prefix over bsum[0..b) itself, scans its chunk
// (deg = cnt+1), writes rowptr + dinv, pre-places self-loops at slot 0.
__global__ __launch_bounds__(256) void k_scan3(const int* __restrict__ cnt,
        const int* __restrict__ bsum, int* __restrict__ rowptr,
        float* __restrict__ dinv, int* __restrict__ col) {
    int b = blockIdx.x, t = threadIdx.x;
    int lane = t & 63, wv = t >> 6;
    __shared__ int wred[4];
    {
        int v = (t < b) ? bsum[t] : 0;   // b <= 98 <= 256
#pragma unroll
        for (int off = 1; off < 64; off <<= 1) v += __shfl_xor(v, off);
        if (lane == 0) wred[wv] = v;
    }
    __syncthreads();
    int pre = (wred[0] + wred[1]) + (wred[2] + wred[3]);
    __syncthreads();

    int i = b * SB + t * 4;
    int c0 = 0, c1 = 0, c2 = 0, c3 = 0;
    if (i + 3 < N_NODES) {
        int4 v = *(const int4*)(cnt + i);
        c0 = v.x; c1 = v.y; c2 = v.z; c3 = v.w;
    } else if (i < N_NODES) {
        c0 = cnt[i];
        if (i + 1 < N_NODES) c1 = cnt[i + 1];
        if (i + 2 < N_NODES) c2 = cnt[i + 2];
    }
    int n0 = (i < N_NODES), n1 = (i + 1 < N_NODES),
        n2 = (i + 2 < N_NODES), n3 = (i + 3 < N_NODES);
    int d0 = c0 + n0, d1 = c1 + n1, d2 = c2 + n2, d3 = c3 + n3;  // degrees
    int s = (d0 + d1) + (d2 + d3);
    int inc = s;
#pragma unroll
    for (int off = 1; off < 64; off <<= 1) {
        int u = __shfl_up(inc, off);
        if (lane >= off) inc += u;
    }
    __shared__ int wtot[4];
    if (lane == 63) wtot[wv] = inc;
    __syncthreads();
    int base = pre + (inc - s);
    for (int w = 0; w < wv; ++w) base += wtot[w];
    if (n0) { rowptr[i]     = base;                dinv[i]     = rsqrtf((float)d0); col[base] = i; }
    if (n1) { rowptr[i + 1] = base + d0;           dinv[i + 1] = rsqrtf((float)d1); col[base + d0] = i + 1; }
    if (n2) { rowptr[i + 2] = base + d0 + d1;      dinv[i + 2] = rsqrtf((float)d2); col[base + d0 + d1] = i + 2; }
    if (n3) { rowptr[i + 3] = base + d0 + d1 + d2; dinv[i + 3] = rsqrtf((float)d3); col[base + d0 + d1 + d2] = i + 3; }
    if (b == 0 && t == 0) rowptr[N_NODES] = E2;
}

// gemm1d: xw1b = bf16(dinv[row] * (x @ W1)) — dinv FOLDED (r0 numerics).
__global__ __launch_bounds__(256) void k_gemm1d(const float* __restrict__ x,
        const unsigned short* __restrict__ W1t, const float* __restrict__ dinv,
        unsigned short* __restrict__ xw1b) {
    int t = threadIdx.x;
    int lane = t & 63, wv = t >> 6;
    int m = lane & 15, quad = lane >> 4;
    bf16x8 B[4][4];
#pragma unroll
    for (int ct = 0; ct < 4; ++ct)
#pragma unroll
        for (int ks = 0; ks < 4; ++ks)
            B[ct][ks] = *(const bf16x8*)(W1t + (size_t)(ct * 16 + m) * IN_C
                                         + ks * 32 + quad * 8);
    int tile = blockIdx.x * 4 + wv;
    if (tile >= NT1) return;
    int rbase = tile * 16;
    const float* xp = x + (size_t)(rbase + m) * IN_C + quad * 8;
    f32x4 c0 = {0.f, 0.f, 0.f, 0.f}, c1 = c0, c2 = c0, c3 = c0;
#pragma unroll
    for (int ks = 0; ks < 4; ++ks) {
        float4 f0 = *(const float4*)(xp + ks * 32);
        float4 f1 = *(const float4*)(xp + ks * 32 + 4);
        bf16x8 a;
        a[0] = (short)f2bf(f0.x); a[1] = (short)f2bf(f0.y);
        a[2] = (short)f2bf(f0.z); a[3] = (short)f2bf(f0.w);
        a[4] = (short)f2bf(f1.x); a[5] = (short)f2bf(f1.y);
        a[6] = (short)f2bf(f1.z); a[7] = (short)f2bf(f1.w);
        c0 = __builtin_amdgcn_mfma_f32_16x16x32_bf16(a, B[0][ks], c0, 0, 0, 0);
        c1 = __builtin_amdgcn_mfma_f32_16x16x32_bf16(a, B[1][ks], c1, 0, 0, 0);
        c2 = __builtin_amdgcn_mfma_f32_16x16x32_bf16(a, B[2][ks], c2, 0, 0, 0);
        c3 = __builtin_amdgcn_mfma_f32_16x16x32_bf16(a, B[3][ks], c3, 0, 0, 0);
    }
    int row0 = rbase + quad * 4;
    float4 dv = *(const float4*)(dinv + row0);   // 16B-aligned (row0 % 4 == 0)
    float dr[4] = {dv.x, dv.y, dv.z, dv.w};
#pragma unroll
    for (int ct = 0; ct < 4; ++ct) {
        f32x4 c = (ct == 0) ? c0 : (ct == 1) ? c1 : (ct == 2) ? c2 : c3;
        unsigned short* p = xw1b + (size_t)row0 * HID + ct * 16 + m;
#pragma unroll
        for (int r = 0; r < 4; ++r) p[(size_t)r * HID] = f2bf(c[r] * dr[r]);
    }
}

// fill: unbanded single-pass scatter, UNFUSED.
// pos = rowptr[d] + 1 + prefix[band][chunk][bin] + rank16[i].
__global__ void k_fill(const int* __restrict__ ei, const int* __restrict__ rowptr,
        const unsigned short* __restrict__ hp16,
        const unsigned short* __restrict__ rank16, int* __restrict__ col) {
    int i = blockIdx.x * 256 + threadIdx.x;  // NFC*256 == N_EDGES exactly
    int d = ei[N_EDGES + i];
    int s = ei[i];
    int r = d / RDIV;
    int bin = d - r * RDIV;
    int k = i / CHUNK;
    unsigned pos = (unsigned)rowptr[d] + 1u
                 + (unsigned)hp16[(size_t)(r * NBK + k) * BINS + bin]
                 + (unsigned)rank16[i];
    col[pos] = s;                           // slot 0 = self-loop
}

// ------- GCN1 aggregate + FUSED attention logits -------
// xw1b already carries dinv[src]: inner loop = shfl + ushort4 load + 4 add.
__global__ __launch_bounds__(256) void k_agg1a(const int* __restrict__ rowptr,
        const int* __restrict__ col, const unsigned short* __restrict__ xw1b,
        const float* __restrict__ dinv, const float* __restrict__ b1,
        const unsigned short* __restrict__ wsdt,
        unsigned short* __restrict__ h1b,
        float* __restrict__ a_s, float* __restrict__ a_d) {
    int t = threadIdx.x;
    int lane = t & 63;
    int d = blockIdx.x * 4 + (t >> 6);
    if (d >= N_NODES) return;
    int start = rowptr[d], end = rowptr[d + 1];
    int sub = lane >> 4;       // which of 4 edges in a group
    int cpos = lane & 15;      // channel quad (4 bf16)
    float4 acc = make_float4(0.f, 0.f, 0.f, 0.f);
    for (int base = start; base < end; base += 64) {
        int cnt = min(64, end - base);
        int sl = (base + lane < end) ? col[base + lane] : 0;
#pragma unroll 4
        for (int j = 0; j < cnt; j += 4) {
            int idx = j + sub;
            int sj = __shfl(sl, idx);
            if (idx < cnt) {
                ushort4 v = ((const ushort4*)(xw1b + (size_t)sj * HID))[cpos];
                acc.x += bf2f(v.x);
                acc.y += bf2f(v.y);
                acc.z += bf2f(v.z);
                acc.w += bf2f(v.w);
            }
        }
    }
    acc.x += __shfl_xor(acc.x, 16); acc.y += __shfl_xor(acc.y, 16);
    acc.z += __shfl_xor(acc.z, 16); acc.w += __shfl_xor(acc.w, 16);
    acc.x += __shfl_xor(acc.x, 32); acc.y += __shfl_xor(acc.y, 32);
    acc.z += __shfl_xor(acc.z, 32); acc.w += __shfl_xor(acc.w, 32);
    // every lane now holds the fully-reduced quad for channels cpos*4..+3
    float di = dinv[d];
    float4 b = ((const float4*)b1)[cpos];
    float h0 = fmaf(acc.x, di, b.x); h0 = h0 > 0.f ? h0 : 0.f;
    float h1 = fmaf(acc.y, di, b.y); h1 = h1 > 0.f ? h1 : 0.f;
    float h2 = fmaf(acc.z, di, b.z); h2 = h2 > 0.f ? h2 : 0.f;
    float h3 = fmaf(acc.w, di, b.w); h3 = h3 > 0.f ? h3 : 0.f;
    ushort4 o = make_ushort4(f2bf(h0), f2bf(h1), f2bf(h2), f2bf(h3));
    if (lane < 16)
        ((ushort4*)(h1b + (size_t)d * HID))[cpos] = o;
    // attention dots on bf16-rounded values (== old k_attn's inputs)
    float r0 = bf2f(o.x), r1 = bf2f(o.y), r2 = bf2f(o.z), r3 = bf2f(o.w);
    int hsel = lane >> 4;                        // head 0..3
    ushort4 ws = ((const ushort4*)(wsdt + hsel * 64))[cpos];
    ushort4 wd = ((const ushort4*)(wsdt + (hsel + 4) * 64))[cpos];
    float ps = r0 * bf2f(ws.x) + r1 * bf2f(ws.y)
             + r2 * bf2f(ws.z) + r3 * bf2f(ws.w);
    float pd = r0 * bf2f(wd.x) + r1 * bf2f(wd.y)
             + r2 * bf2f(wd.z) + r3 * bf2f(wd.w);
#pragma unroll
    for (int mk = 1; mk < 16; mk <<= 1) {
        ps += __shfl_xor(ps, mk);
        pd += __shfl_xor(pd, mk);
    }
    if (cpos == 0) {
        a_s[d * 4 + hsel] = ps;
        a_d[d * 4 + hsel] = pd;
    }
}

// ---------------- GAT aggregate on h1 (agg commutes with W2) ----------------
// r6/r12 form: merged single dispatch, 1 edge/iter, unroll 4.
__global__ __launch_bounds__(256) void k_agg2u(const int* __restrict__ rowptr,
        const int* __restrict__ col, const unsigned short* __restrict__ h1b,
        const float* __restrict__ a_s, const float* __restrict__ a_d,
        unsigned short* __restrict__ ub) {
    __shared__ int   ss[4][64];      // 1 KB
    __shared__ float sp[4][64][4];   // 4 KB
    int t = threadIdx.x;
    int lane = t & 63, wv = t >> 6;
    int d = blockIdx.x * 4 + wv;
    if (d >= N_NODES) return;
    const float4* as4 = (const float4*)a_s;
    float4 adv = ((const float4*)a_d)[d];
    int start = rowptr[d], end = rowptr[d + 1];

    float den0 = 0.f, den1 = 0.f, den2 = 0.f, den3 = 0.f;
    float acc0 = 0.f, acc1 = 0.f, acc2 = 0.f, acc3 = 0.f;
    for (int base = start; base < end; base += 64) {
        int cnt = min(64, end - base);
        float p0 = 0.f, p1 = 0.f, p2 = 0.f, p3 = 0.f;
        int s = 0;
        if (lane < cnt) {
            s = col[base + lane];
            float4 av = as4[s];
            float v;
            v = av.x + adv.x; v = v > 0.f ? v : NEG_SLOPE * v; p0 = __expf(v);
            v = av.y + adv.y; v = v > 0.f ? v : NEG_SLOPE * v; p1 = __expf(v);
            v = av.z + adv.z; v = v > 0.f ? v : NEG_SLOPE * v; p2 = __expf(v);
            v = av.w + adv.w; v = v > 0.f ? v : NEG_SLOPE * v; p3 = __expf(v);
            den0 += p0; den1 += p1; den2 += p2; den3 += p3;
        }
        ss[wv][lane] = s;                                  // wave-private LDS
        ((float4*)sp[wv])[lane] = make_float4(p0, p1, p2, p3);
#pragma unroll 4
        for (int j = 0; j < cnt; ++j) {
            int sj = ss[wv][j];                            // broadcast read
            float4 pj = ((const float4*)sp[wv])[j];        // broadcast read
            float v = bf2f(h1b[(unsigned)sj * 64u + (unsigned)lane]); // 2B/lane
            acc0 = fmaf(pj.x, v, acc0);
            acc1 = fmaf(pj.y, v, acc1);
            acc2 = fmaf(pj.z, v, acc2);
            acc3 = fmaf(pj.w, v, acc3);
        }
    }
#pragma unroll
    for (int mk = 1; mk < 64; mk <<= 1) {
        den0 += __shfl_xor(den0, mk);
        den1 += __shfl_xor(den1, mk);
        den2 += __shfl_xor(den2, mk);
        den3 += __shfl_xor(den3, mk);
    }
    float u0 = acc0 / (den0 + 1e-16f);
    float u1 = acc1 / (den1 + 1e-16f);
    float u2 = acc2 / (den2 + 1e-16f);
    float u3 = acc3 / (den3 + 1e-16f);
    unsigned short* up = ub + (size_t)d * HH;
    up[lane]       = f2bf(u0);
    up[64 + lane]  = f2bf(u1);
    up[128 + lane] = f2bf(u2);
    up[192 + lane] = f2bf(u3);
}

// ---------------- W2-apply + b2 + ELU + W3 + dinv, via MFMA -----------------
__global__ __launch_bounds__(256) void k_gemm3m(const unsigned short* __restrict__ ub,
        const unsigned short* __restrict__ W2t, const float* __restrict__ b2,
        const float* __restrict__ W3, const float* __restrict__ dinv,
        float2* __restrict__ xw3) {
    int t = threadIdx.x;
    int lane = t & 63, wv = t >> 6;
    int m = lane & 15, quad = lane >> 4;
    int nb = wv * 64 + m;            // lane's base output column (head = wv)
    bf16x8 B[4][2];
#pragma unroll
    for (int ct = 0; ct < 4; ++ct)
#pragma unroll
        for (int ks = 0; ks < 2; ++ks)
            B[ct][ks] = *(const bf16x8*)(W2t + (size_t)(nb + ct * 16) * 64
                                         + ks * 32 + quad * 8);
    float bv[4]; float2 w3v[4];
#pragma unroll
    for (int ct = 0; ct < 4; ++ct) {
        int n = nb + ct * 16;
        bv[ct] = b2[n];
        w3v[ct] = ((const float2*)W3)[n];
    }
    __shared__ float red[4][16][2];  // [wave][row][xy]
    int r0 = blockIdx.x * (RT * 16);
    for (int tile = 0; tile < RT; ++tile) {
        int rbase = r0 + tile * 16;
        const unsigned short* ap = ub + (size_t)(rbase + m) * HH + wv * 64 + quad * 8;
        bf16x8 a0 = *(const bf16x8*)(ap);
        bf16x8 a1 = *(const bf16x8*)(ap + 32);
        f32x4 c0 = {0.f, 0.f, 0.f, 0.f}, c1 = c0, c2 = c0, c3 = c0;
        c0 = __builtin_amdgcn_mfma_f32_16x16x32_bf16(a0, B[0][0], c0, 0, 0, 0);
        c1 = __builtin_amdgcn_mfma_f32_16x16x32_bf16(a0, B[1][0], c1, 0, 0, 0);
        c2 = __builtin_amdgcn_mfma_f32_16x16x32_bf16(a0, B[2][0], c2, 0, 0, 0);
        c3 = __builtin_amdgcn_mfma_f32_16x16x32_bf16(a0, B[3][0], c3, 0, 0, 0);
        c0 = __builtin_amdgcn_mfma_f32_16x16x32_bf16(a1, B[0][1], c0, 0, 0, 0);
        c1 = __builtin_amdgcn_mfma_f32_16x16x32_bf16(a1, B[1][1], c1, 0, 0, 0);
        c2 = __builtin_amdgcn_mfma_f32_16x16x32_bf16(a1, B[2][1], c2, 0, 0, 0);
        c3 = __builtin_amdgcn_mfma_f32_16x16x32_bf16(a1, B[3][1], c3, 0, 0, 0);
        float px[4] = {0.f, 0.f, 0.f, 0.f}, py[4] = {0.f, 0.f, 0.f, 0.f};
#pragma unroll
        for (int ct = 0; ct < 4; ++ct) {
            f32x4 c = (ct == 0) ? c0 : (ct == 1) ? c1 : (ct == 2) ? c2 : c3;
#pragma unroll
            for (int r = 0; r < 4; ++r) {
                float o = c[r] + bv[ct];
                o = o > 0.f ? o : expm1f(o);               // ELU
                px[r] = fmaf(o, w3v[ct].x, px[r]);
                py[r] = fmaf(o, w3v[ct].y, py[r]);
            }
        }
#pragma unroll
        for (int mk = 1; mk < 16; mk <<= 1) {
#pragma unroll
            for (int r = 0; r < 4; ++r) {
                px[r] += __shfl_xor(px[r], mk);
                py[r] += __shfl_xor(py[r], mk);
            }
        }
        if (m == 0) {
#pragma unroll
            for (int r = 0; r < 4; ++r) {
                red[wv][quad * 4 + r][0] = px[r];
                red[wv][quad * 4 + r][1] = py[r];
            }
        }
        __syncthreads();
        if (t < 32) {
            int row = t >> 1, xy = t & 1;
            float s = red[0][row][xy] + red[1][row][xy]
                    + red[2][row][xy] + red[3][row][xy];
            ((float*)(xw3 + (rbase + row)))[xy] = s * dinv[rbase + row];
        }
        __syncthreads();
    }
}

// ---------------- GCN2 aggregate: out = dinv[d]*sum_s xw3[s] + b3 -----------
__global__ __launch_bounds__(256) void k_agg3(const int* __restrict__ rowptr,
        const int* __restrict__ col, const float2* __restrict__ xw3,
        const float* __restrict__ dinv, const float* __restrict__ b3,
        float* __restrict__ out) {
    int t = threadIdx.x;
    int lane = t & 63;
    int g = lane >> 2, s = lane & 3;
    int d = blockIdx.x * 64 + (t >> 6) * 16 + g;
    if (d >= N_NODES) return;
    int e0 = rowptr[d], e1 = rowptr[d + 1];
    float a0 = 0.f, a1 = 0.f;
    for (int e = e0 + s; e < e1; e += 4) {
        float2 v = xw3[col[e]];
        a0 += v.x; a1 += v.y;
    }
    a0 += __shfl_xor(a0, 1); a1 += __shfl_xor(a1, 1);
    a0 += __shfl_xor(a0, 2); a1 += __shfl_xor(a1, 2);
    if (s == 0) {
        float di = dinv[d];
        out[d * 2 + 0] = fmaf(a0, di, b3[0]);
        out[d * 2 + 1] = fmaf(a1, di, b3[1]);
    }
}

// ---------------- launch ----------------

extern "C" void kernel_launch(void* const* d_in, const int* in_sizes, int n_in,
                              void* d_out, int out_size, void* d_ws, size_t ws_size,
                              hipStream_t stream) {
    const float* x       = (const float*)d_in[0];
    const int*   ei      = (const int*)d_in[1];
    const float* W1      = (const float*)d_in[2];
    const float* b1      = (const float*)d_in[3];
    const float* W2      = (const float*)d_in[4];
    const float* att_src = (const float*)d_in[5];
    const float* att_dst = (const float*)d_in[6];
    const float* b2      = (const float*)d_in[7];
    const float* W3      = (const float*)d_in[8];
    const float* b3      = (const float*)d_in[9];
    float* out = (float*)d_out;
    (void)in_sizes; (void)n_in; (void)out_size; (void)ws_size;

    char* ws = (char*)d_ws;
    size_t off = 0;
    auto alloc = [&](size_t bytes) -> void* {
        void* p = ws + off;
        off = (off + bytes + 255) & ~(size_t)255;
        return p;
    };
    int*    rowptr = (int*)alloc((N_NODES + 1) * sizeof(int));
    int*    cnt    = (int*)alloc(N_NODES * sizeof(int));
    int*    bsum   = (int*)alloc(NSB * sizeof(int));
    int*    col    = (int*)alloc((size_t)E2 * sizeof(int));
    float*  dinv   = (float*)alloc(N_NODES * sizeof(float));
    unsigned short* W2t  = (unsigned short*)alloc(64 * 256 * sizeof(unsigned short));
    unsigned short* wsdt = (unsigned short*)alloc(16 * 64 * sizeof(unsigned short));
    unsigned short* W1t  = (unsigned short*)alloc(64 * 128 * sizeof(unsigned short));
    unsigned short* xw1b = (unsigned short*)alloc((size_t)N_NODES * HID * sizeof(unsigned short));
    unsigned short* h1b  = (unsigned short*)alloc((size_t)N_NODES * HID * sizeof(unsigned short));
    float*  a_s    = (float*)alloc((size_t)N_NODES * HEADS * sizeof(float));
    float*  a_d    = (float*)alloc((size_t)N_NODES * HEADS * sizeof(float));
    unsigned short* ub   = (unsigned short*)alloc((size_t)N_NODES * HH * sizeof(unsigned short));
    float2* xw3    = (float2*)alloc((size_t)N_NODES * sizeof(float2));
    // hp16 (20 MB) + rank16 (3.2 MB) ALIAS the front of ub (51.2 MB):
    // both dead after k_fill; ub first written by k_agg2u (later in stream).
    unsigned short* hp16   = ub;
    unsigned short* rank16 = ub + (size_t)NHB * BINS;

    k_prep<<<98, 256, 0, stream>>>(W2, W1, att_src, att_dst, W2t, wsdt, W1t, bsum);
    k_hist<<<NHB, HTH, 0, stream>>>(ei, hp16, rank16);
    k_scan1<<<NSB1, 256, 0, stream>>>(hp16, cnt, bsum);
    k_scan3<<<NSB, 256, 0, stream>>>(cnt, bsum, rowptr, dinv, col);
    k_gemm1d<<<NGEMM1, 256, 0, stream>>>(x, W1t, dinv, xw1b);
    k_fill<<<NFC, 256, 0, stream>>>(ei, rowptr, hp16, rank16, col);

    k_agg1a<<<(N_NODES + 3) / 4, 256, 0, stream>>>(rowptr, col, xw1b, dinv, b1,
                                                   wsdt, h1b, a_s, a_d);
    k_agg2u<<<(N_NODES + 3) / 4, 256, 0, stream>>>(rowptr, col, h1b, a_s, a_d, ub);
    k_gemm3m<<<(N_NODES / 16) / RT, 256, 0, stream>>>(ub, W2t, b2, W3, dinv, xw3);
    k_agg3<<<(N_NODES + 63) / 64, 256, 0, stream>>>(rowptr, col, xw3, dinv, b3, out);
}